// Round 11
// baseline (281.337 us; speedup 1.0000x reference)
//
#include <hip/hip_runtime.h>
#include <hip/hip_bf16.h>

typedef unsigned short u16;
typedef float  f32x4  __attribute__((ext_vector_type(4)));
typedef short  bf16x8 __attribute__((ext_vector_type(8)));
typedef u16    u16x4  __attribute__((ext_vector_type(4)));
typedef u16    u16x8  __attribute__((ext_vector_type(8)));

__device__ __forceinline__ u16 f2bf(float f) {
    union { __hip_bfloat16 b; u16 u; } c;
    c.b = __float2bfloat16(f);
    return c.u;
}
__device__ __forceinline__ float bf2f(u16 u) {
    union { unsigned i; float f; } c;
    c.i = ((unsigned)u) << 16;
    return c.f;
}

__device__ __forceinline__ void gl2lds16(const u16* g, u16* l) {
    __builtin_amdgcn_global_load_lds(
        (const __attribute__((address_space(1))) void*)g,
        (__attribute__((address_space(3))) void*)l,
        16, 0, 0);
}

// ---------------------------------------------------------------------------
// Fused prep: blocks [0,4096) x->Xb ; [4096,8192) W converts ;
// [8192,8960) W transposes ; [8960,9728) bias2.
// ---------------------------------------------------------------------------
__global__ __launch_bounds__(256) void prep(const float* __restrict__ x,
                                            const float* __restrict__ Wq,
                                            const float* __restrict__ bq,
                                            const float* __restrict__ Wk,
                                            const float* __restrict__ bk,
                                            const float* __restrict__ Wv,
                                            const float* __restrict__ bv,
                                            const float* __restrict__ Wfc,
                                            u16* __restrict__ Xb,
                                            u16* __restrict__ Wallb,
                                            u16* __restrict__ Wfcb,
                                            u16* __restrict__ Wallt,
                                            float* __restrict__ ball2) {
    const int b = blockIdx.x, tid = threadIdx.x;
    __shared__ u16 t[64][72];
    if (b < 4096) {
        int i = b * 256 + tid;
        float4 v = ((const float4*)x)[i];
        u16x4 o = { f2bf(v.x), f2bf(v.y), f2bf(v.z), f2bf(v.w) };
        ((u16x4*)Xb)[i] = o;
    } else if (b < 8192) {
        int i = b - 4096;
        int z = i >> 10, blk = i & 1023;
        const float* src = z == 0 ? Wq : z == 1 ? Wk : z == 2 ? Wv : Wfc;
        u16* dst = z < 3 ? Wallb + (size_t)z * 1048576 : Wfcb;
        int j = blk * 256 + tid;
        float4 v = ((const float4*)src)[j];
        u16x4 o = { f2bf(v.x), f2bf(v.y), f2bf(v.z), f2bf(v.w) };
        ((u16x4*)dst)[j] = o;
    } else if (b < 8960) {
        int i = b - 8192;
        int z = i >> 8, rem = i & 255;
        const float* src = z == 0 ? Wq : z == 1 ? Wk : Wv;
        u16* dst = Wallt + (size_t)z * 1048576;
        const int tr = (rem >> 4) * 64, tc = (rem & 15) * 64;
        const int r4 = tid >> 4;
        const int c4 = (tid & 15) * 4;
#pragma unroll
        for (int rr = 0; rr < 4; ++rr) {
            int r = rr * 16 + r4;
            float4 v = *(const float4*)&src[(size_t)(tr + r) * 1024 + tc + c4];
            t[r][c4] = f2bf(v.x); t[r][c4 + 1] = f2bf(v.y);
            t[r][c4 + 2] = f2bf(v.z); t[r][c4 + 3] = f2bf(v.w);
        }
        __syncthreads();
#pragma unroll
        for (int rr = 0; rr < 4; ++rr) {
            int oc = rr * 16 + r4;
            u16x4 o = { t[c4][oc], t[c4 + 1][oc], t[c4 + 2][oc], t[c4 + 3][oc] };
            *(u16x4*)&dst[(size_t)(tc + oc) * 1024 + tr + c4] = o;
        }
    } else {
        int i = b - 8960;
        int z = i >> 8, bx = i & 255;
        const float* W = z == 0 ? Wq : z == 1 ? Wk : Wv;
        const float* bias = z == 0 ? bq : z == 1 ? bk : bv;
        const int row  = bx * 4 + (tid >> 6);
        const int lane = tid & 63;
        float4 w  = ((const float4*)(W + (size_t)row * 1024))[lane];
        float4 bb = ((const float4*)bias)[lane];
        float s = w.x * bb.x + w.y * bb.y + w.z * bb.z + w.w * bb.w;
#pragma unroll
        for (int d = 1; d < 64; d <<= 1) s += __shfl_xor(s, d);
        if (lane == 0) ball2[z * 1024 + row] = s + bias[row];
    }
}

// ---------------------------------------------------------------------------
// bf16 V (inside QKV, stride 3072) -> VT[bb][h][dk 64][key 2048] bf16.
// ---------------------------------------------------------------------------
__global__ __launch_bounds__(256) void transV(const u16* __restrict__ QKV,
                                              u16* __restrict__ VT) {
    const int kt = blockIdx.x, bb = blockIdx.y, h = blockIdx.z;
    __shared__ u16 t[64][72];
    const int tid = threadIdx.x;
    {
        const int key = tid >> 3, d8 = (tid & 7) * 8;
        const u16* src = QKV + 2048 +
            ((size_t)(bb * 2048 + kt * 64 + key)) * 3072 + h * 64 + d8;
        *(u16x8*)&t[key][d8]      = *(const u16x8*)src;
        *(u16x8*)&t[key + 32][d8] = *(const u16x8*)(src + (size_t)32 * 3072);
    }
    __syncthreads();
    {
        const int dk = tid >> 3, k8 = (tid & 7) * 8;
        u16* dst = VT + ((size_t)((bb * 16 + h) * 64 + dk)) * 2048 + kt * 64 + k8;
        u16x8 o0, o1;
#pragma unroll
        for (int j = 0; j < 8; ++j) { o0[j] = t[k8 + j][dk]; o1[j] = t[k8 + j][dk + 32]; }
        *(u16x8*)dst = o0;
        *(u16x8*)(dst + (size_t)32 * 2048) = o1;
    }
}

// ---------------------------------------------------------------------------
// C = A @ B^T + bias (+ optional residual xres for OUTF32). m97 structure.
// ---------------------------------------------------------------------------
template<int OUTF32>
__global__ __launch_bounds__(256) void gemm_bt(const u16* __restrict__ A,
                                               const u16* __restrict__ B,
                                               const float* __restrict__ bias,
                                               void* __restrict__ Cout,
                                               int M, int N, int K,
                                               size_t zA, size_t zB, size_t zC,
                                               const float* __restrict__ xres) {
    __shared__ __align__(16) u16 As[128 * 32];
    __shared__ __align__(16) u16 Bs[128 * 32];

    const int tid  = threadIdx.x;
    const int lane = tid & 63;
    const int w    = tid >> 6;
    const int lr   = lane & 15;
    const int lg   = lane >> 4;
    const int wr   = (w >> 1) * 64;
    const int wc   = (w & 1) * 64;
    const int bm   = blockIdx.x * 128;
    const int bn   = blockIdx.y * 128;
    const int z    = blockIdx.z;
    A += (size_t)z * zA;
    B += (size_t)z * zB;
    char* Cz = (char*)Cout + (size_t)z * zC * (OUTF32 ? 4 : 2);

    const int srow = w * 32 + (lane >> 2);
    const int scol = (lane & 3) * 8;
    u16* la = &As[(w * 32) * 32];
    u16* lb = &Bs[(w * 32) * 32];

    f32x4 acc[4][4] = {};

    for (int k0 = 0; k0 < K; k0 += 32) {
        const u16* Ag = A + (size_t)(bm + srow) * K + k0 + scol;
        const u16* Bg = B + (size_t)(bn + srow) * K + k0 + scol;
        gl2lds16(Ag, la);
        gl2lds16(Ag + (size_t)16 * K, la + 16 * 32);
        gl2lds16(Bg, lb);
        gl2lds16(Bg + (size_t)16 * K, lb + 16 * 32);
        __syncthreads();

        bf16x8 af[4], bfr[4];
#pragma unroll
        for (int i = 0; i < 4; ++i)
            af[i] = *(const bf16x8*)&As[(wr + i * 16 + lr) * 32 + lg * 8];
#pragma unroll
        for (int j = 0; j < 4; ++j)
            bfr[j] = *(const bf16x8*)&Bs[(wc + j * 16 + lr) * 32 + lg * 8];
#pragma unroll
        for (int i = 0; i < 4; ++i)
#pragma unroll
            for (int j = 0; j < 4; ++j)
                acc[i][j] = __builtin_amdgcn_mfma_f32_16x16x32_bf16(
                    af[i], bfr[j], acc[i][j], 0, 0, 0);
        __syncthreads();
    }

#pragma unroll
    for (int i = 0; i < 4; ++i) {
        const int grow = bm + wr + i * 16 + lg * 4;
#pragma unroll
        for (int j = 0; j < 4; ++j) {
            const int gcol = bn + wc + j * 16 + lr;
            const float bv = bias ? bias[gcol] : 0.f;
#pragma unroll
            for (int r = 0; r < 4; ++r) {
                float v = acc[i][j][r] + bv;
                if (OUTF32) {
                    if (xres) v += xres[(size_t)(grow + r) * N + gcol];
                    ((float*)Cz)[(size_t)(grow + r) * N + gcol] = v;
                } else {
                    ((u16*)Cz)[(size_t)(grow + r) * N + gcol] = f2bf(v);
                }
            }
        }
    }
}

// ---------------------------------------------------------------------------
// lsumK: standalone softmax-denominator kernel. Block = 128 q-rows of one
// (bb,h); 4 waves x 32 rows (2 groups of 16). K staged in a 3-ring (12 KB),
// single barrier per tile, lookahead-2, vmcnt(2). Writes rl = 1/sum to rl_g.
// ---------------------------------------------------------------------------
__global__ __launch_bounds__(256, 4) void lsumK(const u16* __restrict__ QKV,
                                                float* __restrict__ rl_g) {
    const int hw  = blockIdx.x;                // 0..511
    const int L   = (hw & 7) * 64 + (hw >> 3); // XCD-contiguous
    const int qb  = L & 15;
    const int bbh = L >> 4;
    const int bb  = bbh >> 4;
    const int h   = bbh & 15;
    const int tid = threadIdx.x, lane = tid & 63, w = tid >> 6;
    const int lr = lane & 15, lg = lane >> 4;

    __shared__ __align__(16) u16 smem[12288];

    const int qrow0 = qb * 128 + w * 32;
    bf16x8 qf[2][2];
#pragma unroll
    for (int qg = 0; qg < 2; ++qg) {
        const size_t qoff =
            ((size_t)bb * 2048 + qrow0 + qg * 16 + lr) * 3072 + h * 64 + lg * 8;
        qf[qg][0] = *(const bf16x8*)&QKV[qoff];
        qf[qg][1] = *(const bf16x8*)&QKV[qoff + 32];
    }

    const int srow  = lane >> 3;
    const int sslot = (lane & 7) ^ srow;
    const u16* kg0 = QKV + 1024 + ((size_t)bb * 2048 + w * 16 + srow) * 3072 + h * 64 + sslot * 8;

    const int swz   = (lr & 7) << 3;
    const int offk0 = (lg * 8) ^ swz;
    const int offk1 = (32 + lg * 8) ^ swz;
    const int rowB  = lr * 64;
    const float SC  = 0.18033688011112042f;  // 0.125 * log2(e)

    auto stageKto = [&](int kt, int ldsOff) {
        const u16* s = kg0 + (size_t)kt * 64 * 3072;
        gl2lds16(s,                    smem + ldsOff + (w * 16) * 64);
        gl2lds16(s + (size_t)8 * 3072, smem + ldsOff + (w * 16 + 8) * 64);
    };

    float lsum[2][4] = {};
    stageKto(0, 0);
    stageKto(1, 4096);
    for (int kt = 0; kt < 32; ++kt) {
        if (kt < 31) asm volatile("s_waitcnt vmcnt(2)" ::: "memory");
        else         asm volatile("s_waitcnt vmcnt(0)" ::: "memory");
        __builtin_amdgcn_s_barrier();
        const u16* Kb = smem + (kt % 3) * 4096;
        __builtin_amdgcn_s_setprio(1);
#pragma unroll
        for (int jb = 0; jb < 4; ++jb) {
            bf16x8 kf0 = *(const bf16x8*)&Kb[jb * 1024 + rowB + offk0];
            bf16x8 kf1 = *(const bf16x8*)&Kb[jb * 1024 + rowB + offk1];
#pragma unroll
            for (int qg = 0; qg < 2; ++qg) {
                f32x4 acc = {0.f, 0.f, 0.f, 0.f};
                acc = __builtin_amdgcn_mfma_f32_16x16x32_bf16(qf[qg][0], kf0, acc, 0, 0, 0);
                acc = __builtin_amdgcn_mfma_f32_16x16x32_bf16(qf[qg][1], kf1, acc, 0, 0, 0);
#pragma unroll
                for (int r = 0; r < 4; ++r)
                    lsum[qg][r] += __builtin_amdgcn_exp2f(acc[r] * SC);
            }
        }
        __builtin_amdgcn_s_setprio(0);
        if (kt < 30) stageKto(kt + 2, ((kt + 2) % 3) * 4096);
    }
#pragma unroll
    for (int qg = 0; qg < 2; ++qg)
#pragma unroll
        for (int r = 0; r < 4; ++r) {
#pragma unroll
            for (int d = 1; d < 16; d <<= 1)
                lsum[qg][r] += __shfl_xor(lsum[qg][r], d);
        }
    if (lr == 0) {
        const size_t base = (size_t)(h * 2 + bb) * 2048 + qrow0;
#pragma unroll
        for (int qg = 0; qg < 2; ++qg)
#pragma unroll
            for (int r = 0; r < 4; ++r)
                rl_g[base + qg * 16 + lg * 4 + r] = 1.f / lsum[qg][r];
    }
}

// ---------------------------------------------------------------------------
// PO kernel: R10's winning pass B verbatim, rl read from rl_g.
// vmcnt audit: 4 stage loads + 4 NT stores per iter; queue at wait of iter kt
// = [stage(kt) 4, stores(kt-1) 4, stage(kt+1) 4] -> vmcnt(8); head/tail 4.
// ---------------------------------------------------------------------------
__global__ __launch_bounds__(256, 4) void attnPO(const u16* __restrict__ QKV,
                                                 const u16* __restrict__ VT,
                                                 const float* __restrict__ rl_g,
                                                 float* __restrict__ P,
                                                 u16* __restrict__ O) {
    const int hw  = blockIdx.x;                 // 0..1023
    const int L   = (hw & 7) * 128 + (hw >> 3);
    const int qb  = L & 31;
    const int bbh = L >> 5;
    const int bb  = bbh >> 4;
    const int h   = bbh & 15;
    const int tid = threadIdx.x, lane = tid & 63, w = tid >> 6;
    const int lr = lane & 15, lg = lane >> 4;

    __shared__ __align__(16) u16 smem[20480];

    const int qrow0 = qb * 64 + w * 16;
    const size_t qoff = ((size_t)bb * 2048 + qrow0 + lr) * 3072 + h * 64 + lg * 8;
    const bf16x8 qf0 = *(const bf16x8*)&QKV[qoff];
    const bf16x8 qf1 = *(const bf16x8*)&QKV[qoff + 32];

    const size_t prowb = (size_t)(h * 2 + bb) * 2048 + qrow0;
    float rl[4];
#pragma unroll
    for (int r = 0; r < 4; ++r) rl[r] = rl_g[prowb + lg * 4 + r];

    const int srow  = lane >> 3;
    const int sslot = (lane & 7) ^ srow;
    const u16* kg0 = QKV + 1024 + ((size_t)bb * 2048 + w * 16 + srow) * 3072 + h * 64 + sslot * 8;
    const u16* vg0 = VT + ((size_t)((bb * 16 + h) * 64) + w * 16 + srow) * 2048 + sslot * 8;

    const int swz   = (lr & 7) << 3;
    const int offk0 = (lg * 8) ^ swz;
    const int offk1 = (32 + lg * 8) ^ swz;
    const int rowB  = lr * 64;
    const float SC  = 0.18033688011112042f;

    auto stageKto = [&](int kt, int ldsOff) {
        const u16* s = kg0 + (size_t)kt * 64 * 3072;
        gl2lds16(s,                    smem + ldsOff + (w * 16) * 64);
        gl2lds16(s + (size_t)8 * 3072, smem + ldsOff + (w * 16 + 8) * 64);
    };
    auto stageVto = [&](int kt, int ldsOff) {
        const u16* s = vg0 + kt * 64;
        gl2lds16(s,                    smem + ldsOff + (w * 16) * 64);
        gl2lds16(s + (size_t)8 * 2048, smem + ldsOff + (w * 16 + 8) * 64);
    };

    f32x4 oacc[4] = {};
    const int wrow = lane >> 4;
    const int wcol = (lane & 15) * 4;
    u16* Psw = smem + 16384 + w * 1024;

    stageKto(0, 0); stageVto(0, 8192);
    for (int kt = 0; kt < 32; ++kt) {
        const int cur = kt & 1;
        if (kt == 0) {
            stageKto(1, 4096); stageVto(1, 12288);
            asm volatile("s_waitcnt vmcnt(4)" ::: "memory");
        } else if (kt < 31) {
            stageKto(kt + 1, (cur ^ 1) * 4096);
            stageVto(kt + 1, 8192 + (cur ^ 1) * 4096);
            asm volatile("s_waitcnt vmcnt(8)" ::: "memory");
        } else {
            asm volatile("s_waitcnt vmcnt(4)" ::: "memory");
        }
        __builtin_amdgcn_s_barrier();

        const u16* Kb = smem + cur * 4096;
        const u16* Vb = smem + 8192 + cur * 4096;

        __builtin_amdgcn_s_setprio(1);
#pragma unroll
        for (int jb = 0; jb < 4; ++jb) {
            bf16x8 kf0 = *(const bf16x8*)&Kb[jb * 1024 + rowB + offk0];
            bf16x8 kf1 = *(const bf16x8*)&Kb[jb * 1024 + rowB + offk1];
            f32x4 acc = {0.f, 0.f, 0.f, 0.f};
            acc = __builtin_amdgcn_mfma_f32_16x16x32_bf16(qf0, kf0, acc, 0, 0, 0);
            acc = __builtin_amdgcn_mfma_f32_16x16x32_bf16(qf1, kf1, acc, 0, 0, 0);
#pragma unroll
            for (int r = 0; r < 4; ++r) {
                float p = __builtin_amdgcn_exp2f(acc[r] * SC) * rl[r];
                const int row = lg * 4 + r;
                Psw[row * 64 + ((jb * 16 + lr) ^ ((row & 7) << 3))] = f2bf(p);
            }
        }
        __builtin_amdgcn_s_setprio(0);
        // coalesced P writeback: 4 instrs, each 4 rows x 256B contiguous
#pragma unroll
        for (int rr = 0; rr < 4; ++rr) {
            const int row = rr * 4 + wrow;
            const int s = wcol >> 3, e = wcol & 7;
            u16x4 pb = *(const u16x4*)&Psw[row * 64 + ((s ^ (row & 7)) * 8) + e];
            f32x4 pv = { bf2f(pb[0]), bf2f(pb[1]), bf2f(pb[2]), bf2f(pb[3]) };
            __builtin_nontemporal_store(pv,
                (f32x4*)&P[(prowb + row) * 2048 + kt * 64 + wcol]);
        }
        // PV
        __builtin_amdgcn_s_setprio(1);
#pragma unroll
        for (int kk = 0; kk < 2; ++kk) {
            const int offk = kk ? offk1 : offk0;
            bf16x8 pa = *(const bf16x8*)&Psw[rowB + offk];
#pragma unroll
            for (int dkb = 0; dkb < 4; ++dkb) {
                bf16x8 vb = *(const bf16x8*)&Vb[dkb * 1024 + rowB + offk];
                oacc[dkb] = __builtin_amdgcn_mfma_f32_16x16x32_bf16(pa, vb, oacc[dkb], 0, 0, 0);
            }
        }
        __builtin_amdgcn_s_setprio(0);
        __builtin_amdgcn_s_barrier();
    }

#pragma unroll
    for (int dkb = 0; dkb < 4; ++dkb)
#pragma unroll
        for (int r = 0; r < 4; ++r)
            O[((size_t)bb * 2048 + qrow0 + lg * 4 + r) * 1024 + h * 64 + dkb * 16 + lr] =
                f2bf(oacc[dkb][r]);
}

// ---------------------------------------------------------------------------
// In-place LayerNorm (residual already added in fc GEMM epilogue).
// ---------------------------------------------------------------------------
__global__ __launch_bounds__(256) void ln_only(float* __restrict__ Y,
                                               const float* __restrict__ gamma,
                                               const float* __restrict__ beta) {
    const int row = blockIdx.x, tid = threadIdx.x;
    const int lane = tid & 63, w = tid >> 6;
    float4 y = ((const float4*)(Y + (size_t)row * 1024))[tid];
    float t0 = y.x, t1 = y.y, t2 = y.z, t3 = y.w;
    float s  = t0 + t1 + t2 + t3;
    float ss = t0 * t0 + t1 * t1 + t2 * t2 + t3 * t3;
#pragma unroll
    for (int d = 1; d < 64; d <<= 1) { s += __shfl_xor(s, d); ss += __shfl_xor(ss, d); }
    __shared__ float as_[4], aq_[4];
    if (lane == 0) { as_[w] = s; aq_[w] = ss; }
    __syncthreads();
    s  = as_[0] + as_[1] + as_[2] + as_[3];
    ss = aq_[0] + aq_[1] + aq_[2] + aq_[3];
    const float mu  = s * (1.f / 1024.f);
    const float var = ss * (1.f / 1024.f) - mu * mu;
    const float rs  = rsqrtf(var + 1e-5f);
    float4 g  = ((const float4*)gamma)[tid];
    float4 be = ((const float4*)beta)[tid];
    float4 o;
    o.x = (t0 - mu) * rs * g.x + be.x;
    o.y = (t1 - mu) * rs * g.y + be.y;
    o.z = (t2 - mu) * rs * g.z + be.z;
    o.w = (t3 - mu) * rs * g.w + be.w;
    ((float4*)(Y + (size_t)row * 1024))[tid] = o;
}

// ---------------------------------------------------------------------------
extern "C" void kernel_launch(void* const* d_in, const int* in_sizes, int n_in,
                              void* d_out, int out_size, void* d_ws, size_t ws_size,
                              hipStream_t stream) {
    const float* x     = (const float*)d_in[0];
    const float* Wq    = (const float*)d_in[1];
    const float* bq    = (const float*)d_in[2];
    const float* Wk    = (const float*)d_in[3];
    const float* bk    = (const float*)d_in[4];
    const float* Wv    = (const float*)d_in[5];
    const float* bv    = (const float*)d_in[6];
    const float* Wfc   = (const float*)d_in[7];
    const float* bfc   = (const float*)d_in[8];
    const float* gamma = (const float*)d_in[9];
    const float* beta  = (const float*)d_in[10];

    float* out  = (float*)d_out;
    float* attn = out + (size_t)4194304;  // 16*2*2048*2048 f32

    // d_out[0..16.8MB) slack usage before fc GEMM writes `out`:
    //   VT   @ 0      (8.39 MB bf16)
    //   rl_g @ 9 MB   (256 KB f32)
    u16*   VT   = (u16*)d_out;
    float* rl_g = (float*)((char*)d_out + (size_t)9 * 1048576);

    // ws (34 MB): QKV (4096x3072 bf16) + Ob + Wfcb
    char* ws = (char*)d_ws;
    u16* QKV  = (u16*)(ws);
    u16* Ob   = (u16*)(ws + (size_t)24 * 1048576);
    u16* Wfcb = (u16*)(ws + (size_t)32 * 1048576);

    // pre-attention scratch lives in the (not yet written) attn region
    char* sc = (char*)attn;
    u16*   Xb    = (u16*)sc;                                // 8 MB
    u16*   Wallb = (u16*)(sc + (size_t)8  * 1048576);       // 6 MB
    u16*   Wallt = (u16*)(sc + (size_t)14 * 1048576);       // 6 MB
    u16*   Wall2 = (u16*)(sc + (size_t)20 * 1048576);       // 6 MB
    float* ball2 = (float*)(sc + (size_t)26 * 1048576);     // 12 KB

    const size_t WSZ = 1048576;

    prep<<<9728, 256, 0, stream>>>(x, Wq, bq, Wk, bk, Wv, bv, Wfc,
                                   Xb, Wallb, Wfcb, Wallt, ball2);

    const dim3 blk(256);
    gemm_bt<0><<<dim3(8, 8, 3), blk, 0, stream>>>(Wallb, Wallt, nullptr, Wall2,
                                                  1024, 1024, 1024, WSZ, WSZ, WSZ, nullptr);
    gemm_bt<0><<<dim3(32, 24), blk, 0, stream>>>(Xb, Wall2, ball2, QKV,
                                                 4096, 3072, 1024, 0, 0, 0, nullptr);

    lsumK<<<512, 256, 0, stream>>>(QKV, rl_g);
    transV<<<dim3(32, 2, 16), 256, 0, stream>>>(QKV, VT);
    attnPO<<<1024, 256, 0, stream>>>(QKV, VT, rl_g, attn, Ob);

    // fc + residual -> f32 directly into d_out, then LN in place
    gemm_bt<1><<<dim3(32, 8), blk, 0, stream>>>(Ob, Wfcb, bfc, out,
                                                4096, 1024, 1024, 0, 0, 0, x);
    ln_only<<<4096, 256, 0, stream>>>(out, gamma, beta);
}

// Round 12
// 274.846 us; speedup vs baseline: 1.0236x; 1.0236x over previous
//
#include <hip/hip_runtime.h>
#include <hip/hip_bf16.h>

typedef unsigned short u16;
typedef float  f32x4  __attribute__((ext_vector_type(4)));
typedef short  bf16x8 __attribute__((ext_vector_type(8)));
typedef u16    u16x4  __attribute__((ext_vector_type(4)));
typedef u16    u16x8  __attribute__((ext_vector_type(8)));

__device__ __forceinline__ u16 f2bf(float f) {
    union { __hip_bfloat16 b; u16 u; } c;
    c.b = __float2bfloat16(f);
    return c.u;
}
__device__ __forceinline__ float bf2f(u16 u) {
    union { unsigned i; float f; } c;
    c.i = ((unsigned)u) << 16;
    return c.f;
}

__device__ __forceinline__ void gl2lds16(const u16* g, u16* l) {
    __builtin_amdgcn_global_load_lds(
        (const __attribute__((address_space(1))) void*)g,
        (__attribute__((address_space(3))) void*)l,
        16, 0, 0);
}

// ---------------------------------------------------------------------------
// Fused prep: blocks [0,4096) x->Xb ; [4096,8192) W converts ;
// [8192,8960) W transposes ; [8960,9728) bias2.
// ---------------------------------------------------------------------------
__global__ __launch_bounds__(256) void prep(const float* __restrict__ x,
                                            const float* __restrict__ Wq,
                                            const float* __restrict__ bq,
                                            const float* __restrict__ Wk,
                                            const float* __restrict__ bk,
                                            const float* __restrict__ Wv,
                                            const float* __restrict__ bv,
                                            const float* __restrict__ Wfc,
                                            u16* __restrict__ Xb,
                                            u16* __restrict__ Wallb,
                                            u16* __restrict__ Wfcb,
                                            u16* __restrict__ Wallt,
                                            float* __restrict__ ball2) {
    const int b = blockIdx.x, tid = threadIdx.x;
    __shared__ u16 t[64][72];
    if (b < 4096) {
        int i = b * 256 + tid;
        float4 v = ((const float4*)x)[i];
        u16x4 o = { f2bf(v.x), f2bf(v.y), f2bf(v.z), f2bf(v.w) };
        ((u16x4*)Xb)[i] = o;
    } else if (b < 8192) {
        int i = b - 4096;
        int z = i >> 10, blk = i & 1023;
        const float* src = z == 0 ? Wq : z == 1 ? Wk : z == 2 ? Wv : Wfc;
        u16* dst = z < 3 ? Wallb + (size_t)z * 1048576 : Wfcb;
        int j = blk * 256 + tid;
        float4 v = ((const float4*)src)[j];
        u16x4 o = { f2bf(v.x), f2bf(v.y), f2bf(v.z), f2bf(v.w) };
        ((u16x4*)dst)[j] = o;
    } else if (b < 8960) {
        int i = b - 8192;
        int z = i >> 8, rem = i & 255;
        const float* src = z == 0 ? Wq : z == 1 ? Wk : Wv;
        u16* dst = Wallt + (size_t)z * 1048576;
        const int tr = (rem >> 4) * 64, tc = (rem & 15) * 64;
        const int r4 = tid >> 4;
        const int c4 = (tid & 15) * 4;
#pragma unroll
        for (int rr = 0; rr < 4; ++rr) {
            int r = rr * 16 + r4;
            float4 v = *(const float4*)&src[(size_t)(tr + r) * 1024 + tc + c4];
            t[r][c4] = f2bf(v.x); t[r][c4 + 1] = f2bf(v.y);
            t[r][c4 + 2] = f2bf(v.z); t[r][c4 + 3] = f2bf(v.w);
        }
        __syncthreads();
#pragma unroll
        for (int rr = 0; rr < 4; ++rr) {
            int oc = rr * 16 + r4;
            u16x4 o = { t[c4][oc], t[c4 + 1][oc], t[c4 + 2][oc], t[c4 + 3][oc] };
            *(u16x4*)&dst[(size_t)(tc + oc) * 1024 + tr + c4] = o;
        }
    } else {
        int i = b - 8960;
        int z = i >> 8, bx = i & 255;
        const float* W = z == 0 ? Wq : z == 1 ? Wk : Wv;
        const float* bias = z == 0 ? bq : z == 1 ? bk : bv;
        const int row  = bx * 4 + (tid >> 6);
        const int lane = tid & 63;
        float4 w  = ((const float4*)(W + (size_t)row * 1024))[lane];
        float4 bb = ((const float4*)bias)[lane];
        float s = w.x * bb.x + w.y * bb.y + w.z * bb.z + w.w * bb.w;
#pragma unroll
        for (int d = 1; d < 64; d <<= 1) s += __shfl_xor(s, d);
        if (lane == 0) ball2[z * 1024 + row] = s + bias[row];
    }
}

// ---------------------------------------------------------------------------
// C = A @ B^T + bias (+ optional residual xres for OUTF32). m97 structure.
// ---------------------------------------------------------------------------
template<int OUTF32>
__global__ __launch_bounds__(256) void gemm_bt(const u16* __restrict__ A,
                                               const u16* __restrict__ B,
                                               const float* __restrict__ bias,
                                               void* __restrict__ Cout,
                                               int M, int N, int K,
                                               size_t zA, size_t zB, size_t zC,
                                               const float* __restrict__ xres) {
    __shared__ __align__(16) u16 As[128 * 32];
    __shared__ __align__(16) u16 Bs[128 * 32];

    const int tid  = threadIdx.x;
    const int lane = tid & 63;
    const int w    = tid >> 6;
    const int lr   = lane & 15;
    const int lg   = lane >> 4;
    const int wr   = (w >> 1) * 64;
    const int wc   = (w & 1) * 64;
    const int bm   = blockIdx.x * 128;
    const int bn   = blockIdx.y * 128;
    const int z    = blockIdx.z;
    A += (size_t)z * zA;
    B += (size_t)z * zB;
    char* Cz = (char*)Cout + (size_t)z * zC * (OUTF32 ? 4 : 2);

    const int srow = w * 32 + (lane >> 2);
    const int scol = (lane & 3) * 8;
    u16* la = &As[(w * 32) * 32];
    u16* lb = &Bs[(w * 32) * 32];

    f32x4 acc[4][4] = {};

    for (int k0 = 0; k0 < K; k0 += 32) {
        const u16* Ag = A + (size_t)(bm + srow) * K + k0 + scol;
        const u16* Bg = B + (size_t)(bn + srow) * K + k0 + scol;
        gl2lds16(Ag, la);
        gl2lds16(Ag + (size_t)16 * K, la + 16 * 32);
        gl2lds16(Bg, lb);
        gl2lds16(Bg + (size_t)16 * K, lb + 16 * 32);
        __syncthreads();

        bf16x8 af[4], bfr[4];
#pragma unroll
        for (int i = 0; i < 4; ++i)
            af[i] = *(const bf16x8*)&As[(wr + i * 16 + lr) * 32 + lg * 8];
#pragma unroll
        for (int j = 0; j < 4; ++j)
            bfr[j] = *(const bf16x8*)&Bs[(wc + j * 16 + lr) * 32 + lg * 8];
#pragma unroll
        for (int i = 0; i < 4; ++i)
#pragma unroll
            for (int j = 0; j < 4; ++j)
                acc[i][j] = __builtin_amdgcn_mfma_f32_16x16x32_bf16(
                    af[i], bfr[j], acc[i][j], 0, 0, 0);
        __syncthreads();
    }

#pragma unroll
    for (int i = 0; i < 4; ++i) {
        const int grow = bm + wr + i * 16 + lg * 4;
#pragma unroll
        for (int j = 0; j < 4; ++j) {
            const int gcol = bn + wc + j * 16 + lr;
            const float bv = bias ? bias[gcol] : 0.f;
#pragma unroll
            for (int r = 0; r < 4; ++r) {
                float v = acc[i][j][r] + bv;
                if (OUTF32) {
                    if (xres) v += xres[(size_t)(grow + r) * N + gcol];
                    ((float*)Cz)[(size_t)(grow + r) * N + gcol] = v;
                } else {
                    ((u16*)Cz)[(size_t)(grow + r) * N + gcol] = f2bf(v);
                }
            }
        }
    }
}

// ---------------------------------------------------------------------------
// lsumTV: blocks [0,1024) = softmax denominator (QBLK=64, R9 pass-A geometry,
// 3-ring K, single barrier, vmcnt(2)); blocks [1024,2048) = V transpose.
// ---------------------------------------------------------------------------
__global__ __launch_bounds__(256, 4) void lsumTV(const u16* __restrict__ QKV,
                                                 float* __restrict__ rl_g,
                                                 u16* __restrict__ VT) {
    __shared__ __align__(16) u16 smem[12288];
    const int tid = threadIdx.x;

    if (blockIdx.x >= 1024) {
        // ---- transV: 64x64 tile transpose of V into VT ----
        const int i  = blockIdx.x - 1024;
        const int kt = i & 31, bb = (i >> 5) & 1, h = i >> 6;
        {
            const int key = tid >> 3, d8 = (tid & 7) * 8;
            const u16* src = QKV + 2048 +
                ((size_t)(bb * 2048 + kt * 64 + key)) * 3072 + h * 64 + d8;
            *(u16x8*)&smem[key * 72 + d8]        = *(const u16x8*)src;
            *(u16x8*)&smem[(key + 32) * 72 + d8] = *(const u16x8*)(src + (size_t)32 * 3072);
        }
        __syncthreads();
        {
            const int dk = tid >> 3, k8 = (tid & 7) * 8;
            u16* dst = VT + ((size_t)((bb * 16 + h) * 64 + dk)) * 2048 + kt * 64 + k8;
            u16x8 o0, o1;
#pragma unroll
            for (int j = 0; j < 8; ++j) {
                o0[j] = smem[(k8 + j) * 72 + dk];
                o1[j] = smem[(k8 + j) * 72 + dk + 32];
            }
            *(u16x8*)dst = o0;
            *(u16x8*)(dst + (size_t)32 * 2048) = o1;
        }
        return;
    }

    // ---- lsum: QBLK=64, 4 waves x 16 rows ----
    const int hw  = blockIdx.x;                 // 0..1023
    const int L   = (hw & 7) * 128 + (hw >> 3);
    const int qb  = L & 31;
    const int bbh = L >> 5;
    const int bb  = bbh >> 4;
    const int h   = bbh & 15;
    const int lane = tid & 63, w = tid >> 6;
    const int lr = lane & 15, lg = lane >> 4;

    const int qrow0 = qb * 64 + w * 16;
    const size_t qoff = ((size_t)bb * 2048 + qrow0 + lr) * 3072 + h * 64 + lg * 8;
    const bf16x8 qf0 = *(const bf16x8*)&QKV[qoff];
    const bf16x8 qf1 = *(const bf16x8*)&QKV[qoff + 32];

    const int srow  = lane >> 3;
    const int sslot = (lane & 7) ^ srow;
    const u16* kg0 = QKV + 1024 + ((size_t)bb * 2048 + w * 16 + srow) * 3072 + h * 64 + sslot * 8;

    const int swz   = (lr & 7) << 3;
    const int offk0 = (lg * 8) ^ swz;
    const int offk1 = (32 + lg * 8) ^ swz;
    const int rowB  = lr * 64;
    const float SC  = 0.18033688011112042f;  // 0.125 * log2(e)

    auto stageKto = [&](int kt, int ldsOff) {
        const u16* s = kg0 + (size_t)kt * 64 * 3072;
        gl2lds16(s,                    smem + ldsOff + (w * 16) * 64);
        gl2lds16(s + (size_t)8 * 3072, smem + ldsOff + (w * 16 + 8) * 64);
    };

    float lsum[4] = {0.f, 0.f, 0.f, 0.f};
    stageKto(0, 0);
    stageKto(1, 4096);
    for (int kt = 0; kt < 32; ++kt) {
        if (kt < 31) asm volatile("s_waitcnt vmcnt(2)" ::: "memory");
        else         asm volatile("s_waitcnt vmcnt(0)" ::: "memory");
        __builtin_amdgcn_s_barrier();
        const u16* Kb = smem + (kt % 3) * 4096;
        __builtin_amdgcn_s_setprio(1);
#pragma unroll
        for (int jb = 0; jb < 4; ++jb) {
            bf16x8 kf0 = *(const bf16x8*)&Kb[jb * 1024 + rowB + offk0];
            bf16x8 kf1 = *(const bf16x8*)&Kb[jb * 1024 + rowB + offk1];
            f32x4 acc = {0.f, 0.f, 0.f, 0.f};
            acc = __builtin_amdgcn_mfma_f32_16x16x32_bf16(qf0, kf0, acc, 0, 0, 0);
            acc = __builtin_amdgcn_mfma_f32_16x16x32_bf16(qf1, kf1, acc, 0, 0, 0);
#pragma unroll
            for (int r = 0; r < 4; ++r)
                lsum[r] += __builtin_amdgcn_exp2f(acc[r] * SC);
        }
        __builtin_amdgcn_s_setprio(0);
        if (kt < 30) stageKto(kt + 2, ((kt + 2) % 3) * 4096);
    }
#pragma unroll
    for (int r = 0; r < 4; ++r) {
#pragma unroll
        for (int d = 1; d < 16; d <<= 1) lsum[r] += __shfl_xor(lsum[r], d);
    }
    if (lr == 0) {
        const size_t base = (size_t)(h * 2 + bb) * 2048 + qrow0;
#pragma unroll
        for (int r = 0; r < 4; ++r)
            rl_g[base + lg * 4 + r] = 1.f / lsum[r];
    }
}

// ---------------------------------------------------------------------------
// PO kernel, single barrier per iteration.
// Order: vmcnt -> barrier -> stage(kt+1) -> QK -> P-store -> PV.
// RAW: own stage(kt) retired pre-barrier => visible to all post-barrier.
// WAR: stage(kt+1) overwrites buf(kt-1); its reads completed before
//      barrier(kt) (they feed MFMAs pre-barrier).
// vmcnt: queue at wait of iter kt = [stage(kt) 4, stores(kt-1) 4]
//        -> vmcnt(4); kt==0 -> vmcnt(0).
// ---------------------------------------------------------------------------
__global__ __launch_bounds__(256, 4) void attnPO(const u16* __restrict__ QKV,
                                                 const u16* __restrict__ VT,
                                                 const float* __restrict__ rl_g,
                                                 float* __restrict__ P,
                                                 u16* __restrict__ O) {
    const int hw  = blockIdx.x;                 // 0..1023
    const int L   = (hw & 7) * 128 + (hw >> 3);
    const int qb  = L & 31;
    const int bbh = L >> 5;
    const int bb  = bbh >> 4;
    const int h   = bbh & 15;
    const int tid = threadIdx.x, lane = tid & 63, w = tid >> 6;
    const int lr = lane & 15, lg = lane >> 4;

    __shared__ __align__(16) u16 smem[20480];

    const int qrow0 = qb * 64 + w * 16;
    const size_t qoff = ((size_t)bb * 2048 + qrow0 + lr) * 3072 + h * 64 + lg * 8;
    const bf16x8 qf0 = *(const bf16x8*)&QKV[qoff];
    const bf16x8 qf1 = *(const bf16x8*)&QKV[qoff + 32];

    const size_t prowb = (size_t)(h * 2 + bb) * 2048 + qrow0;
    float rl[4];
#pragma unroll
    for (int r = 0; r < 4; ++r) rl[r] = rl_g[prowb + lg * 4 + r];

    const int srow  = lane >> 3;
    const int sslot = (lane & 7) ^ srow;
    const u16* kg0 = QKV + 1024 + ((size_t)bb * 2048 + w * 16 + srow) * 3072 + h * 64 + sslot * 8;
    const u16* vg0 = VT + ((size_t)((bb * 16 + h) * 64) + w * 16 + srow) * 2048 + sslot * 8;

    const int swz   = (lr & 7) << 3;
    const int offk0 = (lg * 8) ^ swz;
    const int offk1 = (32 + lg * 8) ^ swz;
    const int rowB  = lr * 64;
    const float SC  = 0.18033688011112042f;

    auto stageKto = [&](int kt, int ldsOff) {
        const u16* s = kg0 + (size_t)kt * 64 * 3072;
        gl2lds16(s,                    smem + ldsOff + (w * 16) * 64);
        gl2lds16(s + (size_t)8 * 3072, smem + ldsOff + (w * 16 + 8) * 64);
    };
    auto stageVto = [&](int kt, int ldsOff) {
        const u16* s = vg0 + kt * 64;
        gl2lds16(s,                    smem + ldsOff + (w * 16) * 64);
        gl2lds16(s + (size_t)8 * 2048, smem + ldsOff + (w * 16 + 8) * 64);
    };

    f32x4 oacc[4] = {};
    const int wrow = lane >> 4;
    const int wcol = (lane & 15) * 4;
    u16* Psw = smem + 16384 + w * 1024;

    stageKto(0, 0); stageVto(0, 8192);
    for (int kt = 0; kt < 32; ++kt) {
        const int cur = kt & 1;
        if (kt == 0) asm volatile("s_waitcnt vmcnt(0)" ::: "memory");
        else         asm volatile("s_waitcnt vmcnt(4)" ::: "memory");
        __builtin_amdgcn_s_barrier();
        if (kt < 31) {
            stageKto(kt + 1, (cur ^ 1) * 4096);
            stageVto(kt + 1, 8192 + (cur ^ 1) * 4096);
        }

        const u16* Kb = smem + cur * 4096;
        const u16* Vb = smem + 8192 + cur * 4096;

        __builtin_amdgcn_s_setprio(1);
#pragma unroll
        for (int jb = 0; jb < 4; ++jb) {
            bf16x8 kf0 = *(const bf16x8*)&Kb[jb * 1024 + rowB + offk0];
            bf16x8 kf1 = *(const bf16x8*)&Kb[jb * 1024 + rowB + offk1];
            f32x4 acc = {0.f, 0.f, 0.f, 0.f};
            acc = __builtin_amdgcn_mfma_f32_16x16x32_bf16(qf0, kf0, acc, 0, 0, 0);
            acc = __builtin_amdgcn_mfma_f32_16x16x32_bf16(qf1, kf1, acc, 0, 0, 0);
#pragma unroll
            for (int r = 0; r < 4; ++r) {
                float p = __builtin_amdgcn_exp2f(acc[r] * SC) * rl[r];
                const int row = lg * 4 + r;
                Psw[row * 64 + ((jb * 16 + lr) ^ ((row & 7) << 3))] = f2bf(p);
            }
        }
        __builtin_amdgcn_s_setprio(0);
        // coalesced P writeback: 4 instrs, each 4 rows x 256B contiguous
#pragma unroll
        for (int rr = 0; rr < 4; ++rr) {
            const int row = rr * 4 + wrow;
            const int s = wcol >> 3, e = wcol & 7;
            u16x4 pb = *(const u16x4*)&Psw[row * 64 + ((s ^ (row & 7)) * 8) + e];
            f32x4 pv = { bf2f(pb[0]), bf2f(pb[1]), bf2f(pb[2]), bf2f(pb[3]) };
            __builtin_nontemporal_store(pv,
                (f32x4*)&P[(prowb + row) * 2048 + kt * 64 + wcol]);
        }
        // PV
        __builtin_amdgcn_s_setprio(1);
#pragma unroll
        for (int kk = 0; kk < 2; ++kk) {
            const int offk = kk ? offk1 : offk0;
            bf16x8 pa = *(const bf16x8*)&Psw[rowB + offk];
#pragma unroll
            for (int dkb = 0; dkb < 4; ++dkb) {
                bf16x8 vb = *(const bf16x8*)&Vb[dkb * 1024 + rowB + offk];
                oacc[dkb] = __builtin_amdgcn_mfma_f32_16x16x32_bf16(pa, vb, oacc[dkb], 0, 0, 0);
            }
        }
        __builtin_amdgcn_s_setprio(0);
    }

#pragma unroll
    for (int dkb = 0; dkb < 4; ++dkb)
#pragma unroll
        for (int r = 0; r < 4; ++r)
            O[((size_t)bb * 2048 + qrow0 + lg * 4 + r) * 1024 + h * 64 + dkb * 16 + lr] =
                f2bf(oacc[dkb][r]);
}

// ---------------------------------------------------------------------------
// In-place LayerNorm (residual already added in fc GEMM epilogue).
// ---------------------------------------------------------------------------
__global__ __launch_bounds__(256) void ln_only(float* __restrict__ Y,
                                               const float* __restrict__ gamma,
                                               const float* __restrict__ beta) {
    const int row = blockIdx.x, tid = threadIdx.x;
    const int lane = tid & 63, w = tid >> 6;
    float4 y = ((const float4*)(Y + (size_t)row * 1024))[tid];
    float t0 = y.x, t1 = y.y, t2 = y.z, t3 = y.w;
    float s  = t0 + t1 + t2 + t3;
    float ss = t0 * t0 + t1 * t1 + t2 * t2 + t3 * t3;
#pragma unroll
    for (int d = 1; d < 64; d <<= 1) { s += __shfl_xor(s, d); ss += __shfl_xor(ss, d); }
    __shared__ float as_[4], aq_[4];
    if (lane == 0) { as_[w] = s; aq_[w] = ss; }
    __syncthreads();
    s  = as_[0] + as_[1] + as_[2] + as_[3];
    ss = aq_[0] + aq_[1] + aq_[2] + aq_[3];
    const float mu  = s * (1.f / 1024.f);
    const float var = ss * (1.f / 1024.f) - mu * mu;
    const float rs  = rsqrtf(var + 1e-5f);
    float4 g  = ((const float4*)gamma)[tid];
    float4 be = ((const float4*)beta)[tid];
    float4 o;
    o.x = (t0 - mu) * rs * g.x + be.x;
    o.y = (t1 - mu) * rs * g.y + be.y;
    o.z = (t2 - mu) * rs * g.z + be.z;
    o.w = (t3 - mu) * rs * g.w + be.w;
    ((float4*)(Y + (size_t)row * 1024))[tid] = o;
}

// ---------------------------------------------------------------------------
extern "C" void kernel_launch(void* const* d_in, const int* in_sizes, int n_in,
                              void* d_out, int out_size, void* d_ws, size_t ws_size,
                              hipStream_t stream) {
    const float* x     = (const float*)d_in[0];
    const float* Wq    = (const float*)d_in[1];
    const float* bq    = (const float*)d_in[2];
    const float* Wk    = (const float*)d_in[3];
    const float* bk    = (const float*)d_in[4];
    const float* Wv    = (const float*)d_in[5];
    const float* bv    = (const float*)d_in[6];
    const float* Wfc   = (const float*)d_in[7];
    const float* bfc   = (const float*)d_in[8];
    const float* gamma = (const float*)d_in[9];
    const float* beta  = (const float*)d_in[10];

    float* out  = (float*)d_out;
    float* attn = out + (size_t)4194304;  // 16*2*2048*2048 f32

    // d_out[0..16.8MB) slack usage before fc GEMM writes `out`:
    //   VT   @ 0      (8.39 MB bf16)
    //   rl_g @ 9 MB   (256 KB f32)
    u16*   VT   = (u16*)d_out;
    float* rl_g = (float*)((char*)d_out + (size_t)9 * 1048576);

    // ws (34 MB): QKV (4096x3072 bf16) + Ob + Wfcb
    char* ws = (char*)d_ws;
    u16* QKV  = (u16*)(ws);
    u16* Ob   = (u16*)(ws + (size_t)24 * 1048576);
    u16* Wfcb = (u16*)(ws + (size_t)32 * 1048576);

    // pre-attention scratch lives in the (not yet written) attn region
    char* sc = (char*)attn;
    u16*   Xb    = (u16*)sc;                                // 8 MB
    u16*   Wallb = (u16*)(sc + (size_t)8  * 1048576);       // 6 MB
    u16*   Wallt = (u16*)(sc + (size_t)14 * 1048576);       // 6 MB
    u16*   Wall2 = (u16*)(sc + (size_t)20 * 1048576);       // 6 MB
    float* ball2 = (float*)(sc + (size_t)26 * 1048576);     // 12 KB

    const size_t WSZ = 1048576;

    prep<<<9728, 256, 0, stream>>>(x, Wq, bq, Wk, bk, Wv, bv, Wfc,
                                   Xb, Wallb, Wfcb, Wallt, ball2);

    const dim3 blk(256);
    gemm_bt<0><<<dim3(8, 8, 3), blk, 0, stream>>>(Wallb, Wallt, nullptr, Wall2,
                                                  1024, 1024, 1024, WSZ, WSZ, WSZ, nullptr);
    gemm_bt<0><<<dim3(32, 24), blk, 0, stream>>>(Xb, Wall2, ball2, QKV,
                                                 4096, 3072, 1024, 0, 0, 0, nullptr);

    lsumTV<<<2048, 256, 0, stream>>>(QKV, rl_g, VT);
    attnPO<<<1024, 256, 0, stream>>>(QKV, VT, rl_g, attn, Ob);

    // fc + residual -> f32 directly into d_out, then LN in place
    gemm_bt<1><<<dim3(32, 8), blk, 0, stream>>>(Ob, Wfcb, bfc, out,
                                                4096, 1024, 1024, 0, 0, 0, x);
    ln_only<<<4096, 256, 0, stream>>>(out, gamma, beta);
}